// Round 2
// baseline (303.637 us; speedup 1.0000x reference)
//
#include <hip/hip_runtime.h>
#include <hip/hip_bf16.h>
#include <stdint.h>

// Workspace layout (bytes):
//  outbf  [0,        33554432)   out cast to bf16        (B*T*D)
//  vbf    [33554432, 67108864)   V = out @ W_write^T, bf16
//  wwbf   [67108864, 69206016)   W_write bf16
//  wrbf   [69206016, 71303168)   W_read  bf16
//  intra  [71303168, 104857600)  intra reads bf16 (flat B,T,D layout)
//  U      [104857600,138412032)  per-chunk outer products bf16 [BH][64][64*64]
//  Wst    [138412032,171966464)  pre-chunk W states bf16 [BH][64][64*64]
//  reads  [171966464,205520896)  alpha*(inter+intra) bf16 (flat B,T,D)

typedef __bf16 bf16x8 __attribute__((ext_vector_type(8)));
typedef float f32x4 __attribute__((ext_vector_type(4)));

#define GAS __attribute__((address_space(1)))
#define LAS __attribute__((address_space(3)))

__device__ __forceinline__ unsigned short f2bf(float f) {
  unsigned u = __float_as_uint(f);
  u = (u + 0x7fffu + ((u >> 16) & 1u)) >> 16;   // RNE
  return (unsigned short)u;
}
__device__ __forceinline__ float bf2f(unsigned short h) {
  return __uint_as_float(((unsigned)h) << 16);
}

// ---------------------------------------------------------------- cast f32->bf16
__global__ __launch_bounds__(256) void cast_f32_to_bf16(
    const float* __restrict__ src, unsigned short* __restrict__ dst, int n8) {
  int i = blockIdx.x * 256 + threadIdx.x;  // handles 8 elements
  if (i >= n8) return;
  const float4* s = (const float4*)src + (size_t)i * 2;
  float4 f0 = s[0], f1 = s[1];
  union { uint4 u4; unsigned short us[8]; } o;
  o.us[0] = f2bf(f0.x); o.us[1] = f2bf(f0.y); o.us[2] = f2bf(f0.z); o.us[3] = f2bf(f0.w);
  o.us[4] = f2bf(f1.x); o.us[5] = f2bf(f1.y); o.us[6] = f2bf(f1.z); o.us[7] = f2bf(f1.w);
  ((uint4*)dst)[i] = o.u4;
}

// both 1024x1024 weights in one launch: i8 < 131072 -> W_write, else W_read
__global__ __launch_bounds__(256) void cast_weights(
    const float* __restrict__ w1, const float* __restrict__ w2,
    unsigned short* __restrict__ dst) {
  int i = blockIdx.x * 256 + threadIdx.x;  // 262144 total (2*1048576/8)
  const float* src = (i < 131072) ? w1 : w2;
  int j = (i < 131072) ? i : i - 131072;
  const float4* s = (const float4*)src + (size_t)j * 2;
  float4 f0 = s[0], f1 = s[1];
  union { uint4 u4; unsigned short us[8]; } o;
  o.us[0] = f2bf(f0.x); o.us[1] = f2bf(f0.y); o.us[2] = f2bf(f0.z); o.us[3] = f2bf(f0.w);
  o.us[4] = f2bf(f1.x); o.us[5] = f2bf(f1.y); o.us[6] = f2bf(f1.z); o.us[7] = f2bf(f1.w);
  ((uint4*)dst)[i] = o.u4;
}

// XCD-aware block swizzle for the 1024-block GEMMs (M/128=128 x N/128=8).
__device__ __forceinline__ void swizzle_bm_bn(int id, int& bm, int& bn) {
  int x = id & 7;
  int s = id >> 3;
  bn = s & 7;
  bm = ((s >> 3) << 3) | x;
}

// Stage one 128x32 K-tile of A and B into ring slots (4 global_load_lds per wave).
#define STAGE4(Adst, Bdst, kofs)                                                            \
  _Pragma("unroll") for (int q = 0; q < 2; q++) {                                           \
    int g = (w * 2 + q) * 16 + lr;                                                          \
    __builtin_amdgcn_global_load_lds((GAS void*)(void*)(Ab + (size_t)g * K + (kofs) + lc),  \
                                     (LAS void*)((Adst) + (w * 2 + q) * 512), 16, 0, 0);    \
    __builtin_amdgcn_global_load_lds((GAS void*)(void*)(Bb + (size_t)g * K + (kofs) + lc),  \
                                     (LAS void*)((Bdst) + (w * 2 + q) * 512), 16, 0, 0);    \
  }

// ---------------------------------------------------------------- GEMM C = A * B^T (bf16 out)
// Ring-4 LDS (64KB), prefetch depth 3, counted vmcnt across raw barriers (no drain-0
// in the main loop). Tile `it` guaranteed landed by per-wave vmcnt + barrier; ring slot
// restaged only after the top barrier proves its previous readers finished.
__global__ __launch_bounds__(256, 4) void gemm_bt_bf16out(
    const unsigned short* __restrict__ A, const unsigned short* __restrict__ B,
    unsigned short* __restrict__ C, int M, int N, int K) {
  __shared__ unsigned short As[4][128 * 32];
  __shared__ unsigned short Bs[4][128 * 32];
  int tid = threadIdx.x;
  int l = tid & 63, w = tid >> 6;
  int bm, bn;
  swizzle_bm_bn(blockIdx.x, bm, bn);
  int wm = (w >> 1) * 64, wn = (w & 1) * 64;
  f32x4 acc[4][4];
#pragma unroll
  for (int mi = 0; mi < 4; mi++)
#pragma unroll
    for (int ni = 0; ni < 4; ni++) acc[mi][ni] = (f32x4){0.f, 0.f, 0.f, 0.f};
  const unsigned short* Ab = A + (size_t)bm * 128 * K;
  const unsigned short* Bb = B + (size_t)bn * 128 * K;
  int lr = l >> 2, lc = (l & 3) * 8;
  int lm = l & 15, q4 = l >> 4;
  const int nit = K >> 5;
  // prologue: tiles 0..2 in flight (12 vm-ops/wave)
#pragma unroll
  for (int t = 0; t < 3; t++) STAGE4(&As[t][0], &Bs[t][0], t << 5)
  for (int it = 0; it < nit; it++) {
    __builtin_amdgcn_s_barrier();          // readers of ring slot (it+3)&3 (iter it-1) done
    if (it + 3 < nit) {
      int t = it + 3;
      STAGE4(&As[t & 3][0], &Bs[t & 3][0], t << 5)
    }
    int rem = nit - 1 - it;               // tiles staged ahead still outstanding-allowed
    if (rem >= 3)      asm volatile("s_waitcnt vmcnt(12)" ::: "memory");
    else if (rem == 2) asm volatile("s_waitcnt vmcnt(8)" ::: "memory");
    else if (rem == 1) asm volatile("s_waitcnt vmcnt(4)" ::: "memory");
    else               asm volatile("s_waitcnt vmcnt(0)" ::: "memory");
    __builtin_amdgcn_s_barrier();          // every wave's tile-it loads landed
    __builtin_amdgcn_sched_barrier(0);
    int buf = it & 3;
    bf16x8 a[4], b[4];
#pragma unroll
    for (int mi = 0; mi < 4; mi++) a[mi] = *(const bf16x8*)&As[buf][(wm + mi * 16 + lm) * 32 + q4 * 8];
#pragma unroll
    for (int ni = 0; ni < 4; ni++) b[ni] = *(const bf16x8*)&Bs[buf][(wn + ni * 16 + lm) * 32 + q4 * 8];
#pragma unroll
    for (int mi = 0; mi < 4; mi++)
#pragma unroll
      for (int ni = 0; ni < 4; ni++)
        acc[mi][ni] = __builtin_amdgcn_mfma_f32_16x16x32_bf16(a[mi], b[ni], acc[mi][ni], 0, 0, 0);
  }
#pragma unroll
  for (int mi = 0; mi < 4; mi++)
#pragma unroll
    for (int ni = 0; ni < 4; ni++) {
      int r0 = bm * 128 + wm + mi * 16 + q4 * 4;
      int col = bn * 128 + wn + ni * 16 + lm;
#pragma unroll
      for (int j = 0; j < 4; j++)
        C[(size_t)(r0 + j) * N + col] = f2bf(acc[mi][ni][j]);
    }
}

// Same ring structure; C = base(bf16) + A*B^T (fp32 out). Base preload happens AFTER
// the prologue stage so tiles 0-2 fly during the 64 scalar base loads.
__global__ __launch_bounds__(256, 4) void gemm_bt_addout(
    const unsigned short* __restrict__ A, const unsigned short* __restrict__ B,
    const unsigned short* __restrict__ base_bf, float* __restrict__ C, int M, int N, int K) {
  __shared__ unsigned short As[4][128 * 32];
  __shared__ unsigned short Bs[4][128 * 32];
  int tid = threadIdx.x;
  int l = tid & 63, w = tid >> 6;
  int bm, bn;
  swizzle_bm_bn(blockIdx.x, bm, bn);
  int wm = (w >> 1) * 64, wn = (w & 1) * 64;
  int lr = l >> 2, lc = (l & 3) * 8;
  int lm = l & 15, q4 = l >> 4;
  const unsigned short* Ab = A + (size_t)bm * 128 * K;
  const unsigned short* Bb = B + (size_t)bn * 128 * K;
  const int nit = K >> 5;
#pragma unroll
  for (int t = 0; t < 3; t++) STAGE4(&As[t][0], &Bs[t][0], t << 5)
  f32x4 acc[4][4];
#pragma unroll
  for (int mi = 0; mi < 4; mi++)
#pragma unroll
    for (int ni = 0; ni < 4; ni++) {
      int r0 = bm * 128 + wm + mi * 16 + q4 * 4;
      int col = bn * 128 + wn + ni * 16 + lm;
#pragma unroll
      for (int j = 0; j < 4; j++)
        acc[mi][ni][j] = bf2f(base_bf[(size_t)(r0 + j) * N + col]);
    }
  for (int it = 0; it < nit; it++) {
    __builtin_amdgcn_s_barrier();
    if (it + 3 < nit) {
      int t = it + 3;
      STAGE4(&As[t & 3][0], &Bs[t & 3][0], t << 5)
    }
    int rem = nit - 1 - it;
    if (rem >= 3)      asm volatile("s_waitcnt vmcnt(12)" ::: "memory");
    else if (rem == 2) asm volatile("s_waitcnt vmcnt(8)" ::: "memory");
    else if (rem == 1) asm volatile("s_waitcnt vmcnt(4)" ::: "memory");
    else               asm volatile("s_waitcnt vmcnt(0)" ::: "memory");
    __builtin_amdgcn_s_barrier();
    __builtin_amdgcn_sched_barrier(0);
    int buf = it & 3;
    bf16x8 a[4], b[4];
#pragma unroll
    for (int mi = 0; mi < 4; mi++) a[mi] = *(const bf16x8*)&As[buf][(wm + mi * 16 + lm) * 32 + q4 * 8];
#pragma unroll
    for (int ni = 0; ni < 4; ni++) b[ni] = *(const bf16x8*)&Bs[buf][(wn + ni * 16 + lm) * 32 + q4 * 8];
#pragma unroll
    for (int mi = 0; mi < 4; mi++)
#pragma unroll
      for (int ni = 0; ni < 4; ni++)
        acc[mi][ni] = __builtin_amdgcn_mfma_f32_16x16x32_bf16(a[mi], b[ni], acc[mi][ni], 0, 0, 0);
  }
#pragma unroll
  for (int mi = 0; mi < 4; mi++)
#pragma unroll
    for (int ni = 0; ni < 4; ni++) {
      int r0 = bm * 128 + wm + mi * 16 + q4 * 4;
      int col = bn * 128 + wn + ni * 16 + lm;
#pragma unroll
      for (int j = 0; j < 4; j++)
        C[(size_t)(r0 + j) * N + col] = acc[mi][ni][j];
    }
}

// ---------------------------------------------------------------- per-chunk local work
// grid (c=64, bh=64), 256 thr. Computes S=rk wk^T masked, intra=(S.M) v, U=(v*g_w)^T wk.
__global__ __launch_bounds__(256) void chunk_local(
    const unsigned short* __restrict__ rkg,   // outbf flat [B*T*D]
    const unsigned short* __restrict__ vg,    // vbf flat
    const float* __restrict__ decay,
    unsigned short* __restrict__ intra_bf,    // flat [B*T*D]
    unsigned short* __restrict__ U_bf) {      // [BH][64][64*64]
  int c = blockIdx.x, bh = blockIdx.y;
  int b = bh >> 4, h = bh & 15;
  int tid = threadIdx.x, l = tid & 63, w = tid >> 6;
  float gamma = 1.0f / (1.0f + __expf(-decay[h]));
  float lg = __logf(gamma);

  __shared__ unsigned short rk_s[64 * 72];
  __shared__ unsigned short wk_s[64 * 72];
  __shared__ unsigned short wkT_s[64 * 72];
  __shared__ unsigned short vT_s[64 * 72];
  __shared__ unsigned short S_s[64 * 72];

  const size_t rowbase = (((size_t)b * 4096 + (size_t)c * 64) * 1024) + h * 64;

#pragma unroll
  for (int r = 0; r < 2; r++) {
    int e = r * 256 + tid;
    int p = e >> 3, seg = e & 7;
    uint4 dr = *(const uint4*)(rkg + rowbase + (size_t)p * 1024 + seg * 8);
    *(uint4*)&rk_s[p * 72 + seg * 8] = dr;
    uint4 dv = *(const uint4*)(vg + rowbase + (size_t)p * 1024 + seg * 8);
    {
      unsigned uu[4] = {dv.x, dv.y, dv.z, dv.w};
#pragma unroll
      for (int qq = 0; qq < 4; qq++) {
        vT_s[(seg * 8 + qq * 2) * 72 + p] = (unsigned short)(uu[qq] & 0xffffu);
        vT_s[(seg * 8 + qq * 2 + 1) * 72 + p] = (unsigned short)(uu[qq] >> 16);
      }
    }
    int tg = c * 64 + p - 1;  // wk = rk shifted right by one token (zero at t=0)
    uint4 dw = make_uint4(0u, 0u, 0u, 0u);
    if (tg >= 0) dw = *(const uint4*)(rkg + ((size_t)b * 4096 + tg) * 1024 + h * 64 + seg * 8);
    *(uint4*)&wk_s[p * 72 + seg * 8] = dw;
    {
      unsigned uu[4] = {dw.x, dw.y, dw.z, dw.w};
#pragma unroll
      for (int qq = 0; qq < 4; qq++) {
        wkT_s[(seg * 8 + qq * 2) * 72 + p] = (unsigned short)(uu[qq] & 0xffffu);
        wkT_s[(seg * 8 + qq * 2 + 1) * 72 + p] = (unsigned short)(uu[qq] >> 16);
      }
    }
  }
  __syncthreads();

  int lm = l & 15, q4 = l >> 4;

  // Phase 1: S = rk @ wk^T, apply mask M, store bf16
  {
    bf16x8 a0 = *(const bf16x8*)&rk_s[(w * 16 + lm) * 72 + q4 * 8];
    bf16x8 a1 = *(const bf16x8*)&rk_s[(w * 16 + lm) * 72 + 32 + q4 * 8];
#pragma unroll
    for (int ni = 0; ni < 4; ni++) {
      bf16x8 b0 = *(const bf16x8*)&wk_s[(ni * 16 + lm) * 72 + q4 * 8];
      bf16x8 b1 = *(const bf16x8*)&wk_s[(ni * 16 + lm) * 72 + 32 + q4 * 8];
      f32x4 acc = {0.f, 0.f, 0.f, 0.f};
      acc = __builtin_amdgcn_mfma_f32_16x16x32_bf16(a0, b0, acc, 0, 0, 0);
      acc = __builtin_amdgcn_mfma_f32_16x16x32_bf16(a1, b1, acc, 0, 0, 0);
#pragma unroll
      for (int j = 0; j < 4; j++) {
        int p = w * 16 + q4 * 4 + j;
        int q = ni * 16 + lm;
        float m = (p > q) ? __expf(lg * (float)(p - 1 - q)) : 0.0f;
        S_s[p * 72 + q] = f2bf(acc[j] * m);
      }
    }
  }
  __syncthreads();

  // Phase 2: intra = (S.M) @ v
  {
    bf16x8 a0 = *(const bf16x8*)&S_s[(w * 16 + lm) * 72 + q4 * 8];
    bf16x8 a1 = *(const bf16x8*)&S_s[(w * 16 + lm) * 72 + 32 + q4 * 8];
#pragma unroll
    for (int ni = 0; ni < 4; ni++) {
      bf16x8 b0 = *(const bf16x8*)&vT_s[(ni * 16 + lm) * 72 + q4 * 8];
      bf16x8 b1 = *(const bf16x8*)&vT_s[(ni * 16 + lm) * 72 + 32 + q4 * 8];
      f32x4 acc = {0.f, 0.f, 0.f, 0.f};
      acc = __builtin_amdgcn_mfma_f32_16x16x32_bf16(a0, b0, acc, 0, 0, 0);
      acc = __builtin_amdgcn_mfma_f32_16x16x32_bf16(a1, b1, acc, 0, 0, 0);
#pragma unroll
      for (int j = 0; j < 4; j++) {
        int p = w * 16 + q4 * 4 + j;
        int i = ni * 16 + lm;
        intra_bf[rowbase + (size_t)p * 1024 + i] = f2bf(acc[j]);
      }
    }
  }

  // Phase 3: U = (v * g_w)^T @ wk
  {
    bf16x8 a0 = *(const bf16x8*)&vT_s[(w * 16 + lm) * 72 + q4 * 8];
    bf16x8 a1 = *(const bf16x8*)&vT_s[(w * 16 + lm) * 72 + 32 + q4 * 8];
#pragma unroll
    for (int jj = 0; jj < 8; jj++) {
      int p0 = q4 * 8 + jj;
      a0[jj] = (__bf16)((float)a0[jj] * __expf(lg * (float)(63 - p0)));
      a1[jj] = (__bf16)((float)a1[jj] * __expf(lg * (float)(63 - (p0 + 32))));
    }
    size_t ub = ((size_t)bh * 64 + c) * 4096;
#pragma unroll
    for (int nj = 0; nj < 4; nj++) {
      bf16x8 b0 = *(const bf16x8*)&wkT_s[(nj * 16 + lm) * 72 + q4 * 8];
      bf16x8 b1 = *(const bf16x8*)&wkT_s[(nj * 16 + lm) * 72 + 32 + q4 * 8];
      f32x4 acc = {0.f, 0.f, 0.f, 0.f};
      acc = __builtin_amdgcn_mfma_f32_16x16x32_bf16(a0, b0, acc, 0, 0, 0);
      acc = __builtin_amdgcn_mfma_f32_16x16x32_bf16(a1, b1, acc, 0, 0, 0);
#pragma unroll
      for (int j = 0; j < 4; j++) {
        int i = w * 16 + q4 * 4 + j;
        int col = nj * 16 + lm;
        U_bf[ub + i * 64 + col] = f2bf(acc[j]);
      }
    }
  }
}

// ---------------------------------------------------------------- parallel weighted prefix scan
__global__ __launch_bounds__(256) void scan_w(
    const unsigned short* __restrict__ U_bf, const float* __restrict__ decay,
    unsigned short* __restrict__ Wst) {
  int nsl = blockIdx.x, bh = blockIdx.y;
  int h = bh & 15;
  float gamma = 1.0f / (1.0f + __expf(-decay[h]));
  float gC = __expf(64.0f * __logf(gamma));
  int n0 = nsl * 512 + threadIdx.x * 2;
  const unsigned short* Ub = U_bf + (size_t)bh * 64 * 4096 + n0;
  unsigned short* Wb = Wst + (size_t)bh * 64 * 4096 + n0;
  float w0 = 0.f, w1 = 0.f;
#pragma unroll
  for (int c = 0; c < 64; c++) {
    unsigned u = *(const unsigned*)(Ub + (size_t)c * 4096);
    ushort2 sv;
    sv.x = f2bf(w0);
    sv.y = f2bf(w1);
    *(ushort2*)(Wb + (size_t)c * 4096) = sv;
    w0 = gC * w0 + bf2f((unsigned short)(u & 0xffffu));
    w1 = gC * w1 + bf2f((unsigned short)(u >> 16));
  }
}

// ---------------------------------------------------------------- inter + combine (parallel)
__global__ __launch_bounds__(256) void inter_combine(
    const unsigned short* __restrict__ rkg, const unsigned short* __restrict__ Wst,
    const unsigned short* __restrict__ intra_bf,
    const float* __restrict__ decay, const float* __restrict__ log_alpha,
    unsigned short* __restrict__ reads_bf) {
  int c = blockIdx.x, bh = blockIdx.y;
  int b = bh >> 4, h = bh & 15;
  int tid = threadIdx.x, l = tid & 63, w = tid >> 6;
  int lm = l & 15, q4 = l >> 4;
  float gamma = 1.0f / (1.0f + __expf(-decay[h]));
  float lg = __logf(gamma);
  float alpha = __expf(log_alpha[h]);

  __shared__ unsigned short rk_s[64 * 72];
  __shared__ unsigned short W_s[64 * 72];
  __shared__ unsigned short in_s[64 * 72];

  const size_t rowbase = (((size_t)b * 4096 + (size_t)c * 64) * 1024) + h * 64;
  const size_t wbase = ((size_t)bh * 64 + c) * 4096;

#pragma unroll
  for (int r = 0; r < 2; r++) {
    int e = r * 256 + tid;
    int p = e >> 3, seg = (e & 7) * 8;
    *(uint4*)&rk_s[p * 72 + seg] = *(const uint4*)(rkg + rowbase + (size_t)p * 1024 + seg);
    *(uint4*)&in_s[p * 72 + seg] = *(const uint4*)(intra_bf + rowbase + (size_t)p * 1024 + seg);
    *(uint4*)&W_s[p * 72 + seg] = *(const uint4*)(Wst + wbase + (size_t)p * 64 + seg);
  }
  __syncthreads();

  // MFMA: wave w covers tokens w*16..w*16+15 (M=16), N=64 in 4 tiles, K=64 in 2 steps
  bf16x8 a0 = *(const bf16x8*)&rk_s[(w * 16 + lm) * 72 + q4 * 8];
  bf16x8 a1 = *(const bf16x8*)&rk_s[(w * 16 + lm) * 72 + 32 + q4 * 8];
#pragma unroll
  for (int ni = 0; ni < 4; ni++) {
    bf16x8 b0 = *(const bf16x8*)&W_s[(ni * 16 + lm) * 72 + q4 * 8];
    bf16x8 b1 = *(const bf16x8*)&W_s[(ni * 16 + lm) * 72 + 32 + q4 * 8];
    f32x4 acc = {0.f, 0.f, 0.f, 0.f};
    acc = __builtin_amdgcn_mfma_f32_16x16x32_bf16(a0, b0, acc, 0, 0, 0);
    acc = __builtin_amdgcn_mfma_f32_16x16x32_bf16(a1, b1, acc, 0, 0, 0);
#pragma unroll
    for (int j = 0; j < 4; j++) {
      int p = w * 16 + q4 * 4 + j;   // token within chunk
      int i = ni * 16 + lm;          // state row (output col)
      float gp = __expf(lg * (float)p);
      reads_bf[rowbase + (size_t)p * 1024 + i] =
          f2bf(alpha * (acc[j] * gp + bf2f(in_s[p * 72 + i])));
    }
  }
}

// ----------------------------------------------------------------
extern "C" void kernel_launch(void* const* d_in, const int* in_sizes, int n_in,
                              void* d_out, int out_size, void* d_ws, size_t ws_size,
                              hipStream_t stream) {
  const float* out_f = (const float*)d_in[0];
  const float* Ww = (const float*)d_in[1];
  const float* Wr = (const float*)d_in[2];
  const float* decay = (const float*)d_in[3];
  const float* lalpha = (const float*)d_in[4];

  char* ws = (char*)d_ws;
  unsigned short* outbf = (unsigned short*)(ws + 0);
  unsigned short* vbf   = (unsigned short*)(ws + 33554432);
  unsigned short* wwbf  = (unsigned short*)(ws + 67108864);  // wrbf adjacent at +2MB
  unsigned short* wrbf  = (unsigned short*)(ws + 69206016);
  unsigned short* intra = (unsigned short*)(ws + 71303168);
  unsigned short* U     = (unsigned short*)(ws + 104857600);
  unsigned short* Wst   = (unsigned short*)(ws + 138412032);
  unsigned short* reads = (unsigned short*)(ws + 171966464);

  cast_f32_to_bf16<<<dim3(8192), 256, 0, stream>>>(out_f, outbf, 16777216 / 8);
  cast_weights<<<dim3(1024), 256, 0, stream>>>(Ww, Wr, wwbf);

  // V = out @ W_write^T   (M=B*T=16384, N=D=1024, K=D=1024)
  gemm_bt_bf16out<<<dim3(1024), 256, 0, stream>>>(outbf, wwbf, vbf, 16384, 1024, 1024);

  chunk_local<<<dim3(64, 64), 256, 0, stream>>>(outbf, vbf, decay, intra, U);

  // parallel scan of W states
  scan_w<<<dim3(8, 64), 256, 0, stream>>>(U, decay, Wst);
  inter_combine<<<dim3(64, 64), 256, 0, stream>>>(outbf, Wst, intra, decay, lalpha, reads);

  // final = out + reads @ W_read^T (base added from bf16 copy)
  gemm_bt_addout<<<dim3(1024), 256, 0, stream>>>(reads, wrbf, outbf, (float*)d_out,
                                                 16384, 1024, 1024);
}

// Round 3
// 285.077 us; speedup vs baseline: 1.0651x; 1.0651x over previous
//
#include <hip/hip_runtime.h>
#include <hip/hip_bf16.h>
#include <stdint.h>

// Workspace layout (bytes):
//  outbf  [0,        33554432)   out cast to bf16        (B*T*D)
//  vbf    [33554432, 67108864)   V = out @ W_write^T, bf16
//  wwbf   [67108864, 69206016)   W_write bf16
//  wrbf   [69206016, 71303168)   W_read  bf16
//  intra  [71303168, 104857600)  intra reads bf16 (flat B,T,D layout)
//  U      [104857600,138412032)  per-chunk outer products bf16 [BH][64][64*64]
//  Wst    [138412032,171966464)  pre-chunk W states bf16 [BH][64][64*64]
//  reads  [171966464,205520896)  alpha*(inter+intra) bf16 (flat B,T,D)

typedef __bf16 bf16x8 __attribute__((ext_vector_type(8)));
typedef float f32x4 __attribute__((ext_vector_type(4)));

#define GAS __attribute__((address_space(1)))
#define LAS __attribute__((address_space(3)))

__device__ __forceinline__ unsigned short f2bf(float f) {
  unsigned u = __float_as_uint(f);
  u = (u + 0x7fffu + ((u >> 16) & 1u)) >> 16;   // RNE
  return (unsigned short)u;
}
__device__ __forceinline__ float bf2f(unsigned short h) {
  return __uint_as_float(((unsigned)h) << 16);
}

// ---------------------------------------------------------------- cast f32->bf16
__global__ __launch_bounds__(256) void cast_f32_to_bf16(
    const float* __restrict__ src, unsigned short* __restrict__ dst, int n8) {
  int i = blockIdx.x * 256 + threadIdx.x;  // handles 8 elements
  if (i >= n8) return;
  const float4* s = (const float4*)src + (size_t)i * 2;
  float4 f0 = s[0], f1 = s[1];
  union { uint4 u4; unsigned short us[8]; } o;
  o.us[0] = f2bf(f0.x); o.us[1] = f2bf(f0.y); o.us[2] = f2bf(f0.z); o.us[3] = f2bf(f0.w);
  o.us[4] = f2bf(f1.x); o.us[5] = f2bf(f1.y); o.us[6] = f2bf(f1.z); o.us[7] = f2bf(f1.w);
  ((uint4*)dst)[i] = o.u4;
}

// both 1024x1024 weights in one launch: i8 < 131072 -> W_write, else W_read
__global__ __launch_bounds__(256) void cast_weights(
    const float* __restrict__ w1, const float* __restrict__ w2,
    unsigned short* __restrict__ dst) {
  int i = blockIdx.x * 256 + threadIdx.x;  // 262144 total (2*1048576/8)
  const float* src = (i < 131072) ? w1 : w2;
  int j = (i < 131072) ? i : i - 131072;
  const float4* s = (const float4*)src + (size_t)j * 2;
  float4 f0 = s[0], f1 = s[1];
  union { uint4 u4; unsigned short us[8]; } o;
  o.us[0] = f2bf(f0.x); o.us[1] = f2bf(f0.y); o.us[2] = f2bf(f0.z); o.us[3] = f2bf(f0.w);
  o.us[4] = f2bf(f1.x); o.us[5] = f2bf(f1.y); o.us[6] = f2bf(f1.z); o.us[7] = f2bf(f1.w);
  ((uint4*)dst)[i] = o.u4;
}

// ---------------------------------------------------------------- 256x256 8-phase GEMM
// C = A*B^T (bf16 out) or C = base + A*B^T (fp32 out). Full T-stack:
// T1 XCD swizzle, T2 LDS XOR-swizzle (bit6^bit9 variant for [128][64]bf16 halves),
// T3 8-phase interleave, T4 counted vmcnt(4) at phases 4/8 only, T5 setprio.
// Geometry: BM=BN=256, BK=64, 512 thr = 8 waves (2M x 4N), per-wave 128x64 out.
// LDS 128KB: [slot 0/1][half: 0=A-lo 1=A-hi 2=B-lo 3=B-hi][128*64].
// Stage map (iter i, K-tiles tA=2i slot0 / tB=2i+1 slot1):
//   P1:A-lo(s1,tB) P2:A-hi(s1,tB) P3:B-lo(s0,tA+2) P4:B-hi(s0,tA+2)
//   P5:A-lo(s0,tA+2) P6:A-hi(s0,tA+2) P7:B-lo(s1,tB+2) P8:B-hi(s1,tB+2)
// Each half restaged only after its last reader phase (barrier-separated).
// vmcnt(4) at P4 end: guarantees slot1 {A:P1,P2 / B:P7,P8 prev} landed for P5.
// vmcnt(4) at P8 end: guarantees slot0 {B:P3,P4 / A:P5,P6} landed for next P1.

#define STG(XB, SLOT, HIDX, HF, KT)                                                  \
  do {                                                                               \
    if ((KT) < nT) {                                                                 \
      _Pragma("unroll") for (int r_ = 0; r_ < 2; r_++)                               \
          __builtin_amdgcn_global_load_lds(                                          \
              (GAS void*)(void*)((XB) +                                              \
                                 (size_t)((HF) * 128 + (tid >> 3) + r_ * 64) * K +   \
                                 ((KT) << 6) + srcc),                                \
              (LAS void*)(&lds[SLOT][HIDX][w64 * 512 + r_ * 4096]), 16, 0, 0);       \
    }                                                                                \
  } while (0)

#define DSRA(SLOT, MH)                                                               \
  _Pragma("unroll") for (int m_ = 0; m_ < 4; m_++)                                   \
  _Pragma("unroll") for (int ks_ = 0; ks_ < 2; ks_++)                                \
      a[m_][ks_] = *(const bf16x8*)&lds[SLOT][aH][((MH) * 64 + m_ * 16 + lm) * 64 +  \
                                                  ((ks_ * 32 + q4 * 8) ^ swz)];

#define DSRB(SLOT, BB, N0)                                                           \
  _Pragma("unroll") for (int n_ = 0; n_ < 2; n_++)                                   \
  _Pragma("unroll") for (int ks_ = 0; ks_ < 2; ks_++)                                \
      BB[n_][ks_] = *(const bf16x8*)&lds[SLOT][bH][(brow0 + ((N0) + n_) * 16 + lm) * 64 + \
                                                   ((ks_ * 32 + q4 * 8) ^ swz)];

#define MMA(MH, BB, N0)                                                              \
  __builtin_amdgcn_s_setprio(1);                                                     \
  _Pragma("unroll") for (int m_ = 0; m_ < 4; m_++)                                   \
  _Pragma("unroll") for (int n_ = 0; n_ < 2; n_++)                                   \
  _Pragma("unroll") for (int ks_ = 0; ks_ < 2; ks_++)                                \
      acc[(MH) * 4 + m_][(N0) + n_] = __builtin_amdgcn_mfma_f32_16x16x32_bf16(       \
          a[m_][ks_], BB[n_][ks_], acc[(MH) * 4 + m_][(N0) + n_], 0, 0, 0);          \
  __builtin_amdgcn_s_setprio(0);

#define BARW                                                                         \
  __builtin_amdgcn_s_barrier();                                                      \
  asm volatile("s_waitcnt lgkmcnt(0)" ::: "memory");                                 \
  __builtin_amdgcn_sched_barrier(0);

#define BARE                                                                         \
  __builtin_amdgcn_s_barrier();                                                      \
  __builtin_amdgcn_sched_barrier(0);

template <bool ADD>
__global__ __launch_bounds__(512, 2) void gemm256(
    const unsigned short* __restrict__ A, const unsigned short* __restrict__ B,
    const unsigned short* __restrict__ base_bf, void* __restrict__ Cout,
    int M, int N, int K) {
  __shared__ unsigned short lds[2][4][8192];
  int tid = threadIdx.x;
  int l = tid & 63, w64 = tid >> 6;
  int lm = l & 15, q4 = l >> 4;
  int swz = ((lm >> 2) & 1) << 5;                       // read-side XOR (elements)
  int srcc = ((tid & 7) * 8) ^ (((tid >> 5) & 1) << 5); // stage-side pre-swizzled src col
  int aH = w64 >> 2;                                    // wave's A half buffer (0/1)
  int bH = 2 + ((w64 & 3) >> 1);                        // wave's B half buffer (2/3)
  int brow0 = (w64 & 1) * 64;                           // local B row base
  int id = blockIdx.x;
  int xcd = id & 7, s = id >> 3;
  int bn = s & 3, bm = (s >> 2) * 8 + xcd;              // 4 bn-blocks/XCD share A panel
  const unsigned short* Ab = A + (size_t)bm * 256 * K;
  const unsigned short* Bb = B + (size_t)bn * 256 * K;
  const int nT = K >> 6, nI = nT >> 1;

  // prologue: stage slot0 full K-tile 0 + slot1 B halves of K-tile 1 (12 loads)
  STG(Bb, 0, 2, 0, 0); STG(Bb, 0, 3, 1, 0);
  STG(Ab, 0, 0, 0, 0); STG(Ab, 0, 1, 1, 0);
  STG(Bb, 1, 2, 0, 1); STG(Bb, 1, 3, 1, 1);
  asm volatile("s_waitcnt vmcnt(4)" ::: "memory");      // K-tile 0 landed; t1-B in flight
  __builtin_amdgcn_s_barrier();
  __builtin_amdgcn_sched_barrier(0);

  f32x4 acc[8][4];
  if constexpr (ADD) {
#pragma unroll
    for (int mh = 0; mh < 2; mh++)
#pragma unroll
      for (int m = 0; m < 4; m++)
#pragma unroll
        for (int nf = 0; nf < 4; nf++) {
          int r0 = bm * 256 + (w64 >> 2) * 128 + mh * 64 + m * 16 + q4 * 4;
          int col = bn * 256 + (w64 & 3) * 64 + nf * 16 + lm;
#pragma unroll
          for (int j = 0; j < 4; j++)
            acc[mh * 4 + m][nf][j] = bf2f(base_bf[(size_t)(r0 + j) * N + col]);
        }
  } else {
#pragma unroll
    for (int mf = 0; mf < 8; mf++)
#pragma unroll
      for (int nf = 0; nf < 4; nf++) acc[mf][nf] = (f32x4){0.f, 0.f, 0.f, 0.f};
  }

  bf16x8 a[4][2], b0[2][2], b1[2][2];
  for (int i = 0; i < nI; i++) {
    int t1 = 2 * i + 1, t2 = 2 * i + 2, t3 = 2 * i + 3;
    // ---- K-tile 2i (slot0) ----
    DSRA(0, 0); DSRB(0, b0, 0); STG(Ab, 1, 0, 0, t1);   // P1
    BARW; MMA(0, b0, 0); BARE;
    DSRB(0, b1, 2); STG(Ab, 1, 1, 1, t1);               // P2
    BARW; MMA(0, b1, 2); BARE;
    DSRA(0, 1); STG(Bb, 0, 2, 0, t2);                   // P3
    BARW; MMA(1, b1, 2); BARE;
    STG(Bb, 0, 3, 1, t2);                               // P4
    BARW; MMA(1, b0, 0);
    if (i < nI - 1) { asm volatile("s_waitcnt vmcnt(4)" ::: "memory"); }
    else            { asm volatile("s_waitcnt vmcnt(0)" ::: "memory"); }
    BARE;
    // ---- K-tile 2i+1 (slot1) ----
    DSRA(1, 0); DSRB(1, b0, 0); STG(Ab, 0, 0, 0, t2);   // P5
    BARW; MMA(0, b0, 0); BARE;
    DSRB(1, b1, 2); STG(Ab, 0, 1, 1, t2);               // P6
    BARW; MMA(0, b1, 2); BARE;
    DSRA(1, 1); STG(Bb, 1, 2, 0, t3);                   // P7
    BARW; MMA(1, b1, 2); BARE;
    STG(Bb, 1, 3, 1, t3);                               // P8
    BARW; MMA(1, b0, 0);
    if (i < nI - 1) { asm volatile("s_waitcnt vmcnt(4)" ::: "memory"); }
    BARE;
  }

#pragma unroll
  for (int mh = 0; mh < 2; mh++)
#pragma unroll
    for (int m = 0; m < 4; m++)
#pragma unroll
      for (int nf = 0; nf < 4; nf++) {
        int r0 = bm * 256 + (w64 >> 2) * 128 + mh * 64 + m * 16 + q4 * 4;
        int col = bn * 256 + (w64 & 3) * 64 + nf * 16 + lm;
#pragma unroll
        for (int j = 0; j < 4; j++) {
          if constexpr (ADD)
            ((float*)Cout)[(size_t)(r0 + j) * N + col] = acc[mh * 4 + m][nf][j];
          else
            ((unsigned short*)Cout)[(size_t)(r0 + j) * N + col] = f2bf(acc[mh * 4 + m][nf][j]);
        }
      }
}

// ---------------------------------------------------------------- per-chunk local work
// grid (c=64, bh=64), 256 thr. Computes S=rk wk^T masked, intra=(S.M) v, U=(v*g_w)^T wk.
__global__ __launch_bounds__(256) void chunk_local(
    const unsigned short* __restrict__ rkg,   // outbf flat [B*T*D]
    const unsigned short* __restrict__ vg,    // vbf flat
    const float* __restrict__ decay,
    unsigned short* __restrict__ intra_bf,    // flat [B*T*D]
    unsigned short* __restrict__ U_bf) {      // [BH][64][64*64]
  int c = blockIdx.x, bh = blockIdx.y;
  int b = bh >> 4, h = bh & 15;
  int tid = threadIdx.x, l = tid & 63, w = tid >> 6;
  float gamma = 1.0f / (1.0f + __expf(-decay[h]));
  float lg = __logf(gamma);

  __shared__ unsigned short rk_s[64 * 72];
  __shared__ unsigned short wk_s[64 * 72];
  __shared__ unsigned short wkT_s[64 * 72];
  __shared__ unsigned short vT_s[64 * 72];
  __shared__ unsigned short S_s[64 * 72];

  const size_t rowbase = (((size_t)b * 4096 + (size_t)c * 64) * 1024) + h * 64;

#pragma unroll
  for (int r = 0; r < 2; r++) {
    int e = r * 256 + tid;
    int p = e >> 3, seg = e & 7;
    uint4 dr = *(const uint4*)(rkg + rowbase + (size_t)p * 1024 + seg * 8);
    *(uint4*)&rk_s[p * 72 + seg * 8] = dr;
    uint4 dv = *(const uint4*)(vg + rowbase + (size_t)p * 1024 + seg * 8);
    {
      unsigned uu[4] = {dv.x, dv.y, dv.z, dv.w};
#pragma unroll
      for (int qq = 0; qq < 4; qq++) {
        vT_s[(seg * 8 + qq * 2) * 72 + p] = (unsigned short)(uu[qq] & 0xffffu);
        vT_s[(seg * 8 + qq * 2 + 1) * 72 + p] = (unsigned short)(uu[qq] >> 16);
      }
    }
    int tg = c * 64 + p - 1;  // wk = rk shifted right by one token (zero at t=0)
    uint4 dw = make_uint4(0u, 0u, 0u, 0u);
    if (tg >= 0) dw = *(const uint4*)(rkg + ((size_t)b * 4096 + tg) * 1024 + h * 64 + seg * 8);
    *(uint4*)&wk_s[p * 72 + seg * 8] = dw;
    {
      unsigned uu[4] = {dw.x, dw.y, dw.z, dw.w};
#pragma unroll
      for (int qq = 0; qq < 4; qq++) {
        wkT_s[(seg * 8 + qq * 2) * 72 + p] = (unsigned short)(uu[qq] & 0xffffu);
        wkT_s[(seg * 8 + qq * 2 + 1) * 72 + p] = (unsigned short)(uu[qq] >> 16);
      }
    }
  }
  __syncthreads();

  int lm = l & 15, q4 = l >> 4;

  // Phase 1: S = rk @ wk^T, apply mask M, store bf16
  {
    bf16x8 a0 = *(const bf16x8*)&rk_s[(w * 16 + lm) * 72 + q4 * 8];
    bf16x8 a1 = *(const bf16x8*)&rk_s[(w * 16 + lm) * 72 + 32 + q4 * 8];
#pragma unroll
    for (int ni = 0; ni < 4; ni++) {
      bf16x8 b0 = *(const bf16x8*)&wk_s[(ni * 16 + lm) * 72 + q4 * 8];
      bf16x8 b1 = *(const bf16x8*)&wk_s[(ni * 16 + lm) * 72 + 32 + q4 * 8];
      f32x4 acc = {0.f, 0.f, 0.f, 0.f};
      acc = __builtin_amdgcn_mfma_f32_16x16x32_bf16(a0, b0, acc, 0, 0, 0);
      acc = __builtin_amdgcn_mfma_f32_16x16x32_bf16(a1, b1, acc, 0, 0, 0);
#pragma unroll
      for (int j = 0; j < 4; j++) {
        int p = w * 16 + q4 * 4 + j;
        int q = ni * 16 + lm;
        float m = (p > q) ? __expf(lg * (float)(p - 1 - q)) : 0.0f;
        S_s[p * 72 + q] = f2bf(acc[j] * m);
      }
    }
  }
  __syncthreads();

  // Phase 2: intra = (S.M) @ v
  {
    bf16x8 a0 = *(const bf16x8*)&S_s[(w * 16 + lm) * 72 + q4 * 8];
    bf16x8 a1 = *(const bf16x8*)&S_s[(w * 16 + lm) * 72 + 32 + q4 * 8];
#pragma unroll
    for (int ni = 0; ni < 4; ni++) {
      bf16x8 b0 = *(const bf16x8*)&vT_s[(ni * 16 + lm) * 72 + q4 * 8];
      bf16x8 b1 = *(const bf16x8*)&vT_s[(ni * 16 + lm) * 72 + 32 + q4 * 8];
      f32x4 acc = {0.f, 0.f, 0.f, 0.f};
      acc = __builtin_amdgcn_mfma_f32_16x16x32_bf16(a0, b0, acc, 0, 0, 0);
      acc = __builtin_amdgcn_mfma_f32_16x16x32_bf16(a1, b1, acc, 0, 0, 0);
#pragma unroll
      for (int j = 0; j < 4; j++) {
        int p = w * 16 + q4 * 4 + j;
        int i = ni * 16 + lm;
        intra_bf[rowbase + (size_t)p * 1024 + i] = f2bf(acc[j]);
      }
    }
  }

  // Phase 3: U = (v * g_w)^T @ wk
  {
    bf16x8 a0 = *(const bf16x8*)&vT_s[(w * 16 + lm) * 72 + q4 * 8];
    bf16x8 a1 = *(const bf16x8*)&vT_s[(w * 16 + lm) * 72 + 32 + q4 * 8];
#pragma unroll
    for (int jj = 0; jj < 8; jj++) {
      int p0 = q4 * 8 + jj;
      a0[jj] = (__bf16)((float)a0[jj] * __expf(lg * (float)(63 - p0)));
      a1[jj] = (__bf16)((float)a1[jj] * __expf(lg * (float)(63 - (p0 + 32))));
    }
    size_t ub = ((size_t)bh * 64 + c) * 4096;
#pragma unroll
    for (int nj = 0; nj < 4; nj++) {
      bf16x8 b0 = *(const bf16x8*)&wkT_s[(nj * 16 + lm) * 72 + q4 * 8];
      bf16x8 b1 = *(const bf16x8*)&wkT_s[(nj * 16 + lm) * 72 + 32 + q4 * 8];
      f32x4 acc = {0.f, 0.f, 0.f, 0.f};
      acc = __builtin_amdgcn_mfma_f32_16x16x32_bf16(a0, b0, acc, 0, 0, 0);
      acc = __builtin_amdgcn_mfma_f32_16x16x32_bf16(a1, b1, acc, 0, 0, 0);
#pragma unroll
      for (int j = 0; j < 4; j++) {
        int i = w * 16 + q4 * 4 + j;
        int col = nj * 16 + lm;
        U_bf[ub + i * 64 + col] = f2bf(acc[j]);
      }
    }
  }
}

// ---------------------------------------------------------------- parallel weighted prefix scan
__global__ __launch_bounds__(256) void scan_w(
    const unsigned short* __restrict__ U_bf, const float* __restrict__ decay,
    unsigned short* __restrict__ Wst) {
  int nsl = blockIdx.x, bh = blockIdx.y;
  int h = bh & 15;
  float gamma = 1.0f / (1.0f + __expf(-decay[h]));
  float gC = __expf(64.0f * __logf(gamma));
  int n0 = nsl * 512 + threadIdx.x * 2;
  const unsigned short* Ub = U_bf + (size_t)bh * 64 * 4096 + n0;
  unsigned short* Wb = Wst + (size_t)bh * 64 * 4096 + n0;
  float w0 = 0.f, w1 = 0.f;
#pragma unroll
  for (int c = 0; c < 64; c++) {
    unsigned u = *(const unsigned*)(Ub + (size_t)c * 4096);
    ushort2 sv;
    sv.x = f2bf(w0);
    sv.y = f2bf(w1);
    *(ushort2*)(Wb + (size_t)c * 4096) = sv;
    w0 = gC * w0 + bf2f((unsigned short)(u & 0xffffu));
    w1 = gC * w1 + bf2f((unsigned short)(u >> 16));
  }
}

// ---------------------------------------------------------------- inter + combine (parallel)
__global__ __launch_bounds__(256) void inter_combine(
    const unsigned short* __restrict__ rkg, const unsigned short* __restrict__ Wst,
    const unsigned short* __restrict__ intra_bf,
    const float* __restrict__ decay, const float* __restrict__ log_alpha,
    unsigned short* __restrict__ reads_bf) {
  int c = blockIdx.x, bh = blockIdx.y;
  int b = bh >> 4, h = bh & 15;
  int tid = threadIdx.x, l = tid & 63, w = tid >> 6;
  int lm = l & 15, q4 = l >> 4;
  float gamma = 1.0f / (1.0f + __expf(-decay[h]));
  float lg = __logf(gamma);
  float alpha = __expf(log_alpha[h]);

  __shared__ unsigned short rk_s[64 * 72];
  __shared__ unsigned short W_s[64 * 72];
  __shared__ unsigned short in_s[64 * 72];

  const size_t rowbase = (((size_t)b * 4096 + (size_t)c * 64) * 1024) + h * 64;
  const size_t wbase = ((size_t)bh * 64 + c) * 4096;

#pragma unroll
  for (int r = 0; r < 2; r++) {
    int e = r * 256 + tid;
    int p = e >> 3, seg = (e & 7) * 8;
    *(uint4*)&rk_s[p * 72 + seg] = *(const uint4*)(rkg + rowbase + (size_t)p * 1024 + seg);
    *(uint4*)&in_s[p * 72 + seg] = *(const uint4*)(intra_bf + rowbase + (size_t)p * 1024 + seg);
    *(uint4*)&W_s[p * 72 + seg] = *(const uint4*)(Wst + wbase + (size_t)p * 64 + seg);
  }
  __syncthreads();

  // MFMA: wave w covers tokens w*16..w*16+15 (M=16), N=64 in 4 tiles, K=64 in 2 steps
  bf16x8 a0 = *(const bf16x8*)&rk_s[(w * 16 + lm) * 72 + q4 * 8];
  bf16x8 a1 = *(const bf16x8*)&rk_s[(w * 16 + lm) * 72 + 32 + q4 * 8];
#pragma unroll
  for (int ni = 0; ni < 4; ni++) {
    bf16x8 b0 = *(const bf16x8*)&W_s[(ni * 16 + lm) * 72 + q4 * 8];
    bf16x8 b1 = *(const bf16x8*)&W_s[(ni * 16 + lm) * 72 + 32 + q4 * 8];
    f32x4 acc = {0.f, 0.f, 0.f, 0.f};
    acc = __builtin_amdgcn_mfma_f32_16x16x32_bf16(a0, b0, acc, 0, 0, 0);
    acc = __builtin_amdgcn_mfma_f32_16x16x32_bf16(a1, b1, acc, 0, 0, 0);
#pragma unroll
    for (int j = 0; j < 4; j++) {
      int p = w * 16 + q4 * 4 + j;   // token within chunk
      int i = ni * 16 + lm;          // state row (output col)
      float gp = __expf(lg * (float)p);
      reads_bf[rowbase + (size_t)p * 1024 + i] =
          f2bf(alpha * (acc[j] * gp + bf2f(in_s[p * 72 + i])));
    }
  }
}

// ----------------------------------------------------------------
extern "C" void kernel_launch(void* const* d_in, const int* in_sizes, int n_in,
                              void* d_out, int out_size, void* d_ws, size_t ws_size,
                              hipStream_t stream) {
  const float* out_f = (const float*)d_in[0];
  const float* Ww = (const float*)d_in[1];
  const float* Wr = (const float*)d_in[2];
  const float* decay = (const float*)d_in[3];
  const float* lalpha = (const float*)d_in[4];

  char* ws = (char*)d_ws;
  unsigned short* outbf = (unsigned short*)(ws + 0);
  unsigned short* vbf   = (unsigned short*)(ws + 33554432);
  unsigned short* wwbf  = (unsigned short*)(ws + 67108864);  // wrbf adjacent at +2MB
  unsigned short* wrbf  = (unsigned short*)(ws + 69206016);
  unsigned short* intra = (unsigned short*)(ws + 71303168);
  unsigned short* U     = (unsigned short*)(ws + 104857600);
  unsigned short* Wst   = (unsigned short*)(ws + 138412032);
  unsigned short* reads = (unsigned short*)(ws + 171966464);

  cast_f32_to_bf16<<<dim3(8192), 256, 0, stream>>>(out_f, outbf, 16777216 / 8);
  cast_weights<<<dim3(1024), 256, 0, stream>>>(Ww, Wr, wwbf);

  // V = out @ W_write^T   (M=B*T=16384, N=D=1024, K=D=1024), 256x256 tiles -> 256 blocks
  gemm256<false><<<dim3(256), 512, 0, stream>>>(outbf, wwbf, nullptr, vbf, 16384, 1024, 1024);

  chunk_local<<<dim3(64, 64), 256, 0, stream>>>(outbf, vbf, decay, intra, U);

  // parallel scan of W states
  scan_w<<<dim3(8, 64), 256, 0, stream>>>(U, decay, Wst);
  inter_combine<<<dim3(64, 64), 256, 0, stream>>>(outbf, Wst, intra, decay, lalpha, reads);

  // final = out + reads @ W_read^T (base added from bf16 copy)
  gemm256<true><<<dim3(256), 512, 0, stream>>>(reads, wrbf, outbf, d_out, 16384, 1024, 1024);
}

// Round 4
// 279.605 us; speedup vs baseline: 1.0860x; 1.0196x over previous
//
#include <hip/hip_runtime.h>
#include <hip/hip_bf16.h>
#include <stdint.h>

// Workspace layout (bytes):
//  outbf  [0,        33554432)   out cast to bf16        (B*T*D)
//  vbf    [33554432, 67108864)   V = out @ W_write^T, bf16
//  wwbf   [67108864, 69206016)   W_write bf16
//  wrbf   [69206016, 71303168)   W_read  bf16
//  intra  [71303168, 104857600)  intra reads bf16 (flat B,T,D layout)
//  U      [104857600,138412032)  per-chunk outer products bf16 [BH][64][64*64]
//  Wst    [138412032,171966464)  pre-chunk W states bf16 [BH][64][64*64]
//  reads  [171966464,205520896)  alpha*(inter+intra) bf16 (flat B,T,D)

typedef __bf16 bf16x8 __attribute__((ext_vector_type(8)));
typedef float f32x4 __attribute__((ext_vector_type(4)));

#define GAS __attribute__((address_space(1)))
#define LAS __attribute__((address_space(3)))

__device__ __forceinline__ unsigned short f2bf(float f) {
  unsigned u = __float_as_uint(f);
  u = (u + 0x7fffu + ((u >> 16) & 1u)) >> 16;   // RNE
  return (unsigned short)u;
}
__device__ __forceinline__ float bf2f(unsigned short h) {
  return __uint_as_float(((unsigned)h) << 16);
}

// ---------------------------------------------------------------- fused cast f32->bf16
// i < 2097152: out (16M elems); else weights (W_write then W_read, contiguous dst).
__global__ __launch_bounds__(256) void cast_all(
    const float* __restrict__ outf, const float* __restrict__ w1,
    const float* __restrict__ w2, unsigned short* __restrict__ outbf,
    unsigned short* __restrict__ wbf) {
  int i = blockIdx.x * 256 + threadIdx.x;
  const float* src;
  uint4* dst;
  int j;
  if (i < 2097152) {
    src = outf; j = i; dst = (uint4*)outbf;
  } else {
    j = i - 2097152;
    dst = (uint4*)wbf;
    if (j < 131072) { src = w1; }
    else { src = w2; j -= 131072; dst += 131072; }
  }
  const float4* s = (const float4*)src + (size_t)j * 2;
  float4 f0 = s[0], f1 = s[1];
  union { uint4 u4; unsigned short us[8]; } o;
  o.us[0] = f2bf(f0.x); o.us[1] = f2bf(f0.y); o.us[2] = f2bf(f0.z); o.us[3] = f2bf(f0.w);
  o.us[4] = f2bf(f1.x); o.us[5] = f2bf(f1.y); o.us[6] = f2bf(f1.z); o.us[7] = f2bf(f1.w);
  dst[(i < 2097152) ? i : (i - 2097152 < 131072 ? i - 2097152 : i - 2097152 - 131072)] = o.u4;
}

// ---------------------------------------------------------------- 256x256 8-phase GEMM
// (unchanged from R3 — best measured GEMM so far)
#define STG(XB, SLOT, HIDX, HF, KT)                                                  \
  do {                                                                               \
    if ((KT) < nT) {                                                                 \
      _Pragma("unroll") for (int r_ = 0; r_ < 2; r_++)                               \
          __builtin_amdgcn_global_load_lds(                                          \
              (GAS void*)(void*)((XB) +                                              \
                                 (size_t)((HF) * 128 + (tid >> 3) + r_ * 64) * K +   \
                                 ((KT) << 6) + srcc),                                \
              (LAS void*)(&lds[SLOT][HIDX][w64 * 512 + r_ * 4096]), 16, 0, 0);       \
    }                                                                                \
  } while (0)

#define DSRA(SLOT, MH)                                                               \
  _Pragma("unroll") for (int m_ = 0; m_ < 4; m_++)                                   \
  _Pragma("unroll") for (int ks_ = 0; ks_ < 2; ks_++)                                \
      a[m_][ks_] = *(const bf16x8*)&lds[SLOT][aH][((MH) * 64 + m_ * 16 + lm) * 64 +  \
                                                  ((ks_ * 32 + q4 * 8) ^ swz)];

#define DSRB(SLOT, BB, N0)                                                           \
  _Pragma("unroll") for (int n_ = 0; n_ < 2; n_++)                                   \
  _Pragma("unroll") for (int ks_ = 0; ks_ < 2; ks_++)                                \
      BB[n_][ks_] = *(const bf16x8*)&lds[SLOT][bH][(brow0 + ((N0) + n_) * 16 + lm) * 64 + \
                                                   ((ks_ * 32 + q4 * 8) ^ swz)];

#define MMA(MH, BB, N0)                                                              \
  __builtin_amdgcn_s_setprio(1);                                                     \
  _Pragma("unroll") for (int m_ = 0; m_ < 4; m_++)                                   \
  _Pragma("unroll") for (int n_ = 0; n_ < 2; n_++)                                   \
  _Pragma("unroll") for (int ks_ = 0; ks_ < 2; ks_++)                                \
      acc[(MH) * 4 + m_][(N0) + n_] = __builtin_amdgcn_mfma_f32_16x16x32_bf16(       \
          a[m_][ks_], BB[n_][ks_], acc[(MH) * 4 + m_][(N0) + n_], 0, 0, 0);          \
  __builtin_amdgcn_s_setprio(0);

#define BARW                                                                         \
  __builtin_amdgcn_s_barrier();                                                      \
  asm volatile("s_waitcnt lgkmcnt(0)" ::: "memory");                                 \
  __builtin_amdgcn_sched_barrier(0);

#define BARE                                                                         \
  __builtin_amdgcn_s_barrier();                                                      \
  __builtin_amdgcn_sched_barrier(0);

template <bool ADD>
__global__ __launch_bounds__(512, 2) void gemm256(
    const unsigned short* __restrict__ A, const unsigned short* __restrict__ B,
    const unsigned short* __restrict__ base_bf, void* __restrict__ Cout,
    int M, int N, int K) {
  __shared__ unsigned short lds[2][4][8192];
  int tid = threadIdx.x;
  int l = tid & 63, w64 = tid >> 6;
  int lm = l & 15, q4 = l >> 4;
  int swz = ((lm >> 2) & 1) << 5;
  int srcc = ((tid & 7) * 8) ^ (((tid >> 5) & 1) << 5);
  int aH = w64 >> 2;
  int bH = 2 + ((w64 & 3) >> 1);
  int brow0 = (w64 & 1) * 64;
  int id = blockIdx.x;
  int xcd = id & 7, s = id >> 3;
  int bn = s & 3, bm = (s >> 2) * 8 + xcd;
  const unsigned short* Ab = A + (size_t)bm * 256 * K;
  const unsigned short* Bb = B + (size_t)bn * 256 * K;
  const int nT = K >> 6, nI = nT >> 1;

  STG(Bb, 0, 2, 0, 0); STG(Bb, 0, 3, 1, 0);
  STG(Ab, 0, 0, 0, 0); STG(Ab, 0, 1, 1, 0);
  STG(Bb, 1, 2, 0, 1); STG(Bb, 1, 3, 1, 1);
  asm volatile("s_waitcnt vmcnt(4)" ::: "memory");
  __builtin_amdgcn_s_barrier();
  __builtin_amdgcn_sched_barrier(0);

  f32x4 acc[8][4];
  if constexpr (ADD) {
#pragma unroll
    for (int mh = 0; mh < 2; mh++)
#pragma unroll
      for (int m = 0; m < 4; m++)
#pragma unroll
        for (int nf = 0; nf < 4; nf++) {
          int r0 = bm * 256 + (w64 >> 2) * 128 + mh * 64 + m * 16 + q4 * 4;
          int col = bn * 256 + (w64 & 3) * 64 + nf * 16 + lm;
#pragma unroll
          for (int j = 0; j < 4; j++)
            acc[mh * 4 + m][nf][j] = bf2f(base_bf[(size_t)(r0 + j) * N + col]);
        }
  } else {
#pragma unroll
    for (int mf = 0; mf < 8; mf++)
#pragma unroll
      for (int nf = 0; nf < 4; nf++) acc[mf][nf] = (f32x4){0.f, 0.f, 0.f, 0.f};
  }

  bf16x8 a[4][2], b0[2][2], b1[2][2];
  for (int i = 0; i < nI; i++) {
    int t1 = 2 * i + 1, t2 = 2 * i + 2, t3 = 2 * i + 3;
    DSRA(0, 0); DSRB(0, b0, 0); STG(Ab, 1, 0, 0, t1);   // P1
    BARW; MMA(0, b0, 0); BARE;
    DSRB(0, b1, 2); STG(Ab, 1, 1, 1, t1);               // P2
    BARW; MMA(0, b1, 2); BARE;
    DSRA(0, 1); STG(Bb, 0, 2, 0, t2);                   // P3
    BARW; MMA(1, b1, 2); BARE;
    STG(Bb, 0, 3, 1, t2);                               // P4
    BARW; MMA(1, b0, 0);
    if (i < nI - 1) { asm volatile("s_waitcnt vmcnt(4)" ::: "memory"); }
    else            { asm volatile("s_waitcnt vmcnt(0)" ::: "memory"); }
    BARE;
    DSRA(1, 0); DSRB(1, b0, 0); STG(Ab, 0, 0, 0, t2);   // P5
    BARW; MMA(0, b0, 0); BARE;
    DSRB(1, b1, 2); STG(Ab, 0, 1, 1, t2);               // P6
    BARW; MMA(0, b1, 2); BARE;
    DSRA(1, 1); STG(Bb, 1, 2, 0, t3);                   // P7
    BARW; MMA(1, b1, 2); BARE;
    STG(Bb, 1, 3, 1, t3);                               // P8
    BARW; MMA(1, b0, 0);
    if (i < nI - 1) { asm volatile("s_waitcnt vmcnt(4)" ::: "memory"); }
    BARE;
  }

#pragma unroll
  for (int mh = 0; mh < 2; mh++)
#pragma unroll
    for (int m = 0; m < 4; m++)
#pragma unroll
      for (int nf = 0; nf < 4; nf++) {
        int r0 = bm * 256 + (w64 >> 2) * 128 + mh * 64 + m * 16 + q4 * 4;
        int col = bn * 256 + (w64 & 3) * 64 + nf * 16 + lm;
#pragma unroll
        for (int j = 0; j < 4; j++) {
          if constexpr (ADD)
            ((float*)Cout)[(size_t)(r0 + j) * N + col] = acc[mh * 4 + m][nf][j];
          else
            ((unsigned short*)Cout)[(size_t)(r0 + j) * N + col] = f2bf(acc[mh * 4 + m][nf][j]);
        }
      }
}

// ---------------------------------------------------------------- per-chunk local work
// grid (c=64, bh=64), 256 thr. S=rk wk^T masked, intra=(S.M) v, U=(v*g_w)^T wk.
// v2: single 65-row krows buffer replaces separate rk/wk streams (-31MB HBM, -1 LDS
// array -> 37KB -> 4 blocks/CU); gamma^d via LDS table (same __expf values, once).
__global__ __launch_bounds__(256) void chunk_local(
    const unsigned short* __restrict__ rkg,   // outbf flat [B*T*D]
    const unsigned short* __restrict__ vg,    // vbf flat
    const float* __restrict__ decay,
    unsigned short* __restrict__ intra_bf,    // flat [B*T*D]
    unsigned short* __restrict__ U_bf) {      // [BH][64][64*64]
  int c = blockIdx.x, bh = blockIdx.y;
  int b = bh >> 4, h = bh & 15;
  int tid = threadIdx.x, l = tid & 63, w = tid >> 6;
  float gamma = 1.0f / (1.0f + __expf(-decay[h]));
  float lg = __logf(gamma);

  __shared__ unsigned short kr_s[65 * 72];   // kr_s[p] = token c*64-1+p (p=0..64)
  __shared__ unsigned short wkT_s[64 * 72];  // transpose of kr_s rows 0..63
  __shared__ unsigned short vT_s[64 * 72];
  __shared__ unsigned short S_s[64 * 72];
  __shared__ float pw_s[64];                 // gamma^d

  if (tid < 64) pw_s[tid] = __expf(lg * (float)tid);

  const size_t rowbase = (((size_t)b * 4096 + (size_t)c * 64) * 1024) + h * 64;
  const size_t bb = (size_t)b * 4096;

#pragma unroll
  for (int r = 0; r < 2; r++) {
    int e = r * 256 + tid;
    int p = e >> 3, seg = e & 7;
    // v row p (token c*64+p) -> transposed
    uint4 dv = *(const uint4*)(vg + rowbase + (size_t)p * 1024 + seg * 8);
    {
      unsigned uu[4] = {dv.x, dv.y, dv.z, dv.w};
#pragma unroll
      for (int qq = 0; qq < 4; qq++) {
        vT_s[(seg * 8 + qq * 2) * 72 + p] = (unsigned short)(uu[qq] & 0xffffu);
        vT_s[(seg * 8 + qq * 2 + 1) * 72 + p] = (unsigned short)(uu[qq] >> 16);
      }
    }
    // k row p = token c*64-1+p (zero row only at c==0,p==0)
    int tg = c * 64 - 1 + p;
    uint4 dw = make_uint4(0u, 0u, 0u, 0u);
    if (tg >= 0) dw = *(const uint4*)(rkg + (bb + tg) * 1024 + h * 64 + seg * 8);
    *(uint4*)&kr_s[p * 72 + seg * 8] = dw;
    {
      unsigned uu[4] = {dw.x, dw.y, dw.z, dw.w};
#pragma unroll
      for (int qq = 0; qq < 4; qq++) {
        wkT_s[(seg * 8 + qq * 2) * 72 + p] = (unsigned short)(uu[qq] & 0xffffu);
        wkT_s[(seg * 8 + qq * 2 + 1) * 72 + p] = (unsigned short)(uu[qq] >> 16);
      }
    }
  }
  if (tid < 8) {  // k row 64 (token c*64+63) — rk's last row, not part of wk
    uint4 dw = *(const uint4*)(rkg + (bb + (size_t)c * 64 + 63) * 1024 + h * 64 + tid * 8);
    *(uint4*)&kr_s[64 * 72 + tid * 8] = dw;
  }
  __syncthreads();

  int lm = l & 15, q4 = l >> 4;

  // Phase 1: S = rk @ wk^T (rk row p = kr_s[p+1], wk row q = kr_s[q]), mask, bf16
  {
    bf16x8 a0 = *(const bf16x8*)&kr_s[(w * 16 + lm + 1) * 72 + q4 * 8];
    bf16x8 a1 = *(const bf16x8*)&kr_s[(w * 16 + lm + 1) * 72 + 32 + q4 * 8];
#pragma unroll
    for (int ni = 0; ni < 4; ni++) {
      bf16x8 b0 = *(const bf16x8*)&kr_s[(ni * 16 + lm) * 72 + q4 * 8];
      bf16x8 b1 = *(const bf16x8*)&kr_s[(ni * 16 + lm) * 72 + 32 + q4 * 8];
      f32x4 acc = {0.f, 0.f, 0.f, 0.f};
      acc = __builtin_amdgcn_mfma_f32_16x16x32_bf16(a0, b0, acc, 0, 0, 0);
      acc = __builtin_amdgcn_mfma_f32_16x16x32_bf16(a1, b1, acc, 0, 0, 0);
#pragma unroll
      for (int j = 0; j < 4; j++) {
        int p = w * 16 + q4 * 4 + j;
        int q = ni * 16 + lm;
        float m = (p > q) ? pw_s[p - 1 - q] : 0.0f;
        S_s[p * 72 + q] = f2bf(acc[j] * m);
      }
    }
  }
  __syncthreads();

  // Phase 2: intra = (S.M) @ v
  {
    bf16x8 a0 = *(const bf16x8*)&S_s[(w * 16 + lm) * 72 + q4 * 8];
    bf16x8 a1 = *(const bf16x8*)&S_s[(w * 16 + lm) * 72 + 32 + q4 * 8];
#pragma unroll
    for (int ni = 0; ni < 4; ni++) {
      bf16x8 b0 = *(const bf16x8*)&vT_s[(ni * 16 + lm) * 72 + q4 * 8];
      bf16x8 b1 = *(const bf16x8*)&vT_s[(ni * 16 + lm) * 72 + 32 + q4 * 8];
      f32x4 acc = {0.f, 0.f, 0.f, 0.f};
      acc = __builtin_amdgcn_mfma_f32_16x16x32_bf16(a0, b0, acc, 0, 0, 0);
      acc = __builtin_amdgcn_mfma_f32_16x16x32_bf16(a1, b1, acc, 0, 0, 0);
#pragma unroll
      for (int j = 0; j < 4; j++) {
        int p = w * 16 + q4 * 4 + j;
        int i = ni * 16 + lm;
        intra_bf[rowbase + (size_t)p * 1024 + i] = f2bf(acc[j]);
      }
    }
  }

  // Phase 3: U = (v * g_w)^T @ wk
  {
    bf16x8 a0 = *(const bf16x8*)&vT_s[(w * 16 + lm) * 72 + q4 * 8];
    bf16x8 a1 = *(const bf16x8*)&vT_s[(w * 16 + lm) * 72 + 32 + q4 * 8];
#pragma unroll
    for (int jj = 0; jj < 8; jj++) {
      int p0 = q4 * 8 + jj;
      a0[jj] = (__bf16)((float)a0[jj] * pw_s[63 - p0]);
      a1[jj] = (__bf16)((float)a1[jj] * pw_s[63 - (p0 + 32)]);
    }
    size_t ub = ((size_t)bh * 64 + c) * 4096;
#pragma unroll
    for (int nj = 0; nj < 4; nj++) {
      bf16x8 b0 = *(const bf16x8*)&wkT_s[(nj * 16 + lm) * 72 + q4 * 8];
      bf16x8 b1 = *(const bf16x8*)&wkT_s[(nj * 16 + lm) * 72 + 32 + q4 * 8];
      f32x4 acc = {0.f, 0.f, 0.f, 0.f};
      acc = __builtin_amdgcn_mfma_f32_16x16x32_bf16(a0, b0, acc, 0, 0, 0);
      acc = __builtin_amdgcn_mfma_f32_16x16x32_bf16(a1, b1, acc, 0, 0, 0);
#pragma unroll
      for (int j = 0; j < 4; j++) {
        int i = w * 16 + q4 * 4 + j;
        int col = nj * 16 + lm;
        U_bf[ub + i * 64 + col] = f2bf(acc[j]);
      }
    }
  }
}

// ---------------------------------------------------------------- parallel weighted prefix scan
// v2: 4 elems/thread via uint2 (8B/lane), grid (4, 64).
__global__ __launch_bounds__(256) void scan_w(
    const unsigned short* __restrict__ U_bf, const float* __restrict__ decay,
    unsigned short* __restrict__ Wst) {
  int nsl = blockIdx.x, bh = blockIdx.y;
  int h = bh & 15;
  float gamma = 1.0f / (1.0f + __expf(-decay[h]));
  float gC = __expf(64.0f * __logf(gamma));
  int n0 = nsl * 1024 + threadIdx.x * 4;
  const unsigned short* Ub = U_bf + (size_t)bh * 64 * 4096 + n0;
  unsigned short* Wb = Wst + (size_t)bh * 64 * 4096 + n0;
  float w0 = 0.f, w1 = 0.f, w2 = 0.f, w3 = 0.f;
#pragma unroll
  for (int c = 0; c < 64; c++) {
    uint2 u = *(const uint2*)(Ub + (size_t)c * 4096);
    ushort4 sv;
    sv.x = f2bf(w0); sv.y = f2bf(w1); sv.z = f2bf(w2); sv.w = f2bf(w3);
    *(ushort4*)(Wb + (size_t)c * 4096) = sv;
    w0 = gC * w0 + bf2f((unsigned short)(u.x & 0xffffu));
    w1 = gC * w1 + bf2f((unsigned short)(u.x >> 16));
    w2 = gC * w2 + bf2f((unsigned short)(u.y & 0xffffu));
    w3 = gC * w3 + bf2f((unsigned short)(u.y >> 16));
  }
}

// ---------------------------------------------------------------- inter + combine (parallel)
__global__ __launch_bounds__(256) void inter_combine(
    const unsigned short* __restrict__ rkg, const unsigned short* __restrict__ Wst,
    const unsigned short* __restrict__ intra_bf,
    const float* __restrict__ decay, const float* __restrict__ log_alpha,
    unsigned short* __restrict__ reads_bf) {
  int c = blockIdx.x, bh = blockIdx.y;
  int b = bh >> 4, h = bh & 15;
  int tid = threadIdx.x, l = tid & 63, w = tid >> 6;
  int lm = l & 15, q4 = l >> 4;
  float gamma = 1.0f / (1.0f + __expf(-decay[h]));
  float lg = __logf(gamma);
  float alpha = __expf(log_alpha[h]);

  __shared__ unsigned short rk_s[64 * 72];
  __shared__ unsigned short W_s[64 * 72];
  __shared__ unsigned short in_s[64 * 72];

  const size_t rowbase = (((size_t)b * 4096 + (size_t)c * 64) * 1024) + h * 64;
  const size_t wbase = ((size_t)bh * 64 + c) * 4096;

#pragma unroll
  for (int r = 0; r < 2; r++) {
    int e = r * 256 + tid;
    int p = e >> 3, seg = (e & 7) * 8;
    *(uint4*)&rk_s[p * 72 + seg] = *(const uint4*)(rkg + rowbase + (size_t)p * 1024 + seg);
    *(uint4*)&in_s[p * 72 + seg] = *(const uint4*)(intra_bf + rowbase + (size_t)p * 1024 + seg);
    *(uint4*)&W_s[p * 72 + seg] = *(const uint4*)(Wst + wbase + (size_t)p * 64 + seg);
  }
  __syncthreads();

  bf16x8 a0 = *(const bf16x8*)&rk_s[(w * 16 + lm) * 72 + q4 * 8];
  bf16x8 a1 = *(const bf16x8*)&rk_s[(w * 16 + lm) * 72 + 32 + q4 * 8];
#pragma unroll
  for (int ni = 0; ni < 4; ni++) {
    bf16x8 b0 = *(const bf16x8*)&W_s[(ni * 16 + lm) * 72 + q4 * 8];
    bf16x8 b1 = *(const bf16x8*)&W_s[(ni * 16 + lm) * 72 + 32 + q4 * 8];
    f32x4 acc = {0.f, 0.f, 0.f, 0.f};
    acc = __builtin_amdgcn_mfma_f32_16x16x32_bf16(a0, b0, acc, 0, 0, 0);
    acc = __builtin_amdgcn_mfma_f32_16x16x32_bf16(a1, b1, acc, 0, 0, 0);
#pragma unroll
    for (int j = 0; j < 4; j++) {
      int p = w * 16 + q4 * 4 + j;
      int i = ni * 16 + lm;
      float gp = __expf(lg * (float)p);
      reads_bf[rowbase + (size_t)p * 1024 + i] =
          f2bf(alpha * (acc[j] * gp + bf2f(in_s[p * 72 + i])));
    }
  }
}

// ----------------------------------------------------------------
extern "C" void kernel_launch(void* const* d_in, const int* in_sizes, int n_in,
                              void* d_out, int out_size, void* d_ws, size_t ws_size,
                              hipStream_t stream) {
  const float* out_f = (const float*)d_in[0];
  const float* Ww = (const float*)d_in[1];
  const float* Wr = (const float*)d_in[2];
  const float* decay = (const float*)d_in[3];
  const float* lalpha = (const float*)d_in[4];

  char* ws = (char*)d_ws;
  unsigned short* outbf = (unsigned short*)(ws + 0);
  unsigned short* vbf   = (unsigned short*)(ws + 33554432);
  unsigned short* wwbf  = (unsigned short*)(ws + 67108864);  // wrbf adjacent at +2MB
  unsigned short* wrbf  = (unsigned short*)(ws + 69206016);
  unsigned short* intra = (unsigned short*)(ws + 71303168);
  unsigned short* U     = (unsigned short*)(ws + 104857600);
  unsigned short* Wst   = (unsigned short*)(ws + 138412032);
  unsigned short* reads = (unsigned short*)(ws + 171966464);

  // fused casts: 2097152 (out) + 262144 (weights) uint4-units / 256 thr = 9216 blocks
  cast_all<<<dim3(9216), 256, 0, stream>>>(out_f, Ww, Wr, outbf, wwbf);

  // V = out @ W_write^T   (M=B*T=16384, N=D=1024, K=D=1024), 256x256 tiles
  gemm256<false><<<dim3(256), 512, 0, stream>>>(outbf, wwbf, nullptr, vbf, 16384, 1024, 1024);

  chunk_local<<<dim3(64, 64), 256, 0, stream>>>(outbf, vbf, decay, intra, U);

  scan_w<<<dim3(4, 64), 256, 0, stream>>>(U, decay, Wst);
  inter_combine<<<dim3(64, 64), 256, 0, stream>>>(outbf, Wst, intra, decay, lalpha, reads);

  // final = out + reads @ W_read^T (base added from bf16 copy)
  gemm256<true><<<dim3(256), 512, 0, stream>>>(reads, wrbf, outbf, d_out, 16384, 1024, 1024);
}

// Round 5
// 274.191 us; speedup vs baseline: 1.1074x; 1.0197x over previous
//
#include <hip/hip_runtime.h>
#include <hip/hip_bf16.h>
#include <stdint.h>

// Workspace layout (bytes):
//  outbf  [0,        33554432)   out cast to bf16        (B*T*D)
//  vbf    [33554432, 67108864)   V = out @ W_write^T, bf16
//  wwbf   [67108864, 69206016)   W_write bf16
//  wrbf   [69206016, 71303168)   W_read  bf16
//  intra  [71303168, 104857600)  intra reads bf16 (flat B,T,D layout)
//  U      [104857600,138412032)  per-chunk outer products bf16 [BH][64][64*64]
//  Wst    [138412032,171966464)  pre-chunk W states bf16 [BH][64][64*64]
//  reads  [171966464,205520896)  alpha*(inter+intra) bf16 (flat B,T,D)

typedef __bf16 bf16x8 __attribute__((ext_vector_type(8)));
typedef float f32x4 __attribute__((ext_vector_type(4)));

#define GAS __attribute__((address_space(1)))
#define LAS __attribute__((address_space(3)))

__device__ __forceinline__ unsigned short f2bf(float f) {
  unsigned u = __float_as_uint(f);
  u = (u + 0x7fffu + ((u >> 16) & 1u)) >> 16;   // RNE
  return (unsigned short)u;
}
__device__ __forceinline__ float bf2f(unsigned short h) {
  return __uint_as_float(((unsigned)h) << 16);
}

// ---------------------------------------------------------------- fused cast f32->bf16
__global__ __launch_bounds__(256) void cast_all(
    const float* __restrict__ outf, const float* __restrict__ w1,
    const float* __restrict__ w2, unsigned short* __restrict__ outbf,
    unsigned short* __restrict__ wbf) {
  int i = blockIdx.x * 256 + threadIdx.x;
  const float* src;
  uint4* dst;
  int j;
  if (i < 2097152) {
    src = outf; j = i; dst = (uint4*)outbf;
  } else {
    j = i - 2097152;
    dst = (uint4*)wbf;
    if (j < 131072) { src = w1; }
    else { src = w2; j -= 131072; dst += 131072; }
  }
  const float4* s = (const float4*)src + (size_t)j * 2;
  float4 f0 = s[0], f1 = s[1];
  union { uint4 u4; unsigned short us[8]; } o;
  o.us[0] = f2bf(f0.x); o.us[1] = f2bf(f0.y); o.us[2] = f2bf(f0.z); o.us[3] = f2bf(f0.w);
  o.us[4] = f2bf(f1.x); o.us[5] = f2bf(f1.y); o.us[6] = f2bf(f1.z); o.us[7] = f2bf(f1.w);
  dst[(i < 2097152) ? i : (i - 2097152 < 131072 ? i - 2097152 : i - 2097152 - 131072)] = o.u4;
}

// ---------------------------------------------------------------- 256x256 8-phase GEMM
// R5: full chunk-uniform XOR swizzle. Row = 128B = 8x16B chunks; LDS slot cs holds
// global chunk cr = cs ^ (row&7). Stage: linear LDS dest (global_load_lds), source
// column pre-swizzled per lane. Read: slot = (ks*4+q4) ^ (lm&7) -> each of the 8
// chunk columns hit exactly 8x per wave-read = zero bank conflicts (structural min).
#define STG(XB, SLOT, HIDX, HF, KT)                                                  \
  do {                                                                               \
    if ((KT) < nT) {                                                                 \
      _Pragma("unroll") for (int r_ = 0; r_ < 2; r_++)                               \
          __builtin_amdgcn_global_load_lds(                                          \
              (GAS void*)(void*)((XB) +                                              \
                                 (size_t)((HF) * 128 + (tid >> 3) + r_ * 64) * K +   \
                                 ((KT) << 6) + srcc),                                \
              (LAS void*)(&lds[SLOT][HIDX][w64 * 512 + r_ * 4096]), 16, 0, 0);       \
    }                                                                                \
  } while (0)

#define DSRA(SLOT, MH)                                                               \
  _Pragma("unroll") for (int m_ = 0; m_ < 4; m_++)                                   \
  _Pragma("unroll") for (int ks_ = 0; ks_ < 2; ks_++)                                \
      a[m_][ks_] = *(const bf16x8*)&lds[SLOT][aH][((MH) * 64 + m_ * 16 + lm) * 64 +  \
                                                  (((ks_ * 4 + q4) ^ lsw) * 8)];

#define DSRB(SLOT, BB, N0)                                                           \
  _Pragma("unroll") for (int n_ = 0; n_ < 2; n_++)                                   \
  _Pragma("unroll") for (int ks_ = 0; ks_ < 2; ks_++)                                \
      BB[n_][ks_] = *(const bf16x8*)&lds[SLOT][bH][(brow0 + ((N0) + n_) * 16 + lm) * 64 + \
                                                   (((ks_ * 4 + q4) ^ lsw) * 8)];

#define MMA(MH, BB, N0)                                                              \
  __builtin_amdgcn_s_setprio(1);                                                     \
  _Pragma("unroll") for (int m_ = 0; m_ < 4; m_++)                                   \
  _Pragma("unroll") for (int n_ = 0; n_ < 2; n_++)                                   \
  _Pragma("unroll") for (int ks_ = 0; ks_ < 2; ks_++)                                \
      acc[(MH) * 4 + m_][(N0) + n_] = __builtin_amdgcn_mfma_f32_16x16x32_bf16(       \
          a[m_][ks_], BB[n_][ks_], acc[(MH) * 4 + m_][(N0) + n_], 0, 0, 0);          \
  __builtin_amdgcn_s_setprio(0);

#define BARW                                                                         \
  __builtin_amdgcn_s_barrier();                                                      \
  asm volatile("s_waitcnt lgkmcnt(0)" ::: "memory");                                 \
  __builtin_amdgcn_sched_barrier(0);

#define BARE                                                                         \
  __builtin_amdgcn_s_barrier();                                                      \
  __builtin_amdgcn_sched_barrier(0);

template <bool ADD>
__global__ __launch_bounds__(512, 2) void gemm256(
    const unsigned short* __restrict__ A, const unsigned short* __restrict__ B,
    const unsigned short* __restrict__ base_bf, void* __restrict__ Cout,
    int M, int N, int K) {
  __shared__ unsigned short lds[2][4][8192];
  int tid = threadIdx.x;
  int l = tid & 63, w64 = tid >> 6;
  int lm = l & 15, q4 = l >> 4;
  int lsw = lm & 7;                                     // read-side XOR (chunk units)
  int srcc = (((tid & 7) ^ ((tid >> 3) & 7)) * 8);      // stage-side pre-swizzled src col
  int aH = w64 >> 2;
  int bH = 2 + ((w64 & 3) >> 1);
  int brow0 = (w64 & 1) * 64;
  int id = blockIdx.x;
  int xcd = id & 7, s = id >> 3;
  int bn = s & 3, bm = (s >> 2) * 8 + xcd;
  const unsigned short* Ab = A + (size_t)bm * 256 * K;
  const unsigned short* Bb = B + (size_t)bn * 256 * K;
  const int nT = K >> 6, nI = nT >> 1;

  STG(Bb, 0, 2, 0, 0); STG(Bb, 0, 3, 1, 0);
  STG(Ab, 0, 0, 0, 0); STG(Ab, 0, 1, 1, 0);
  STG(Bb, 1, 2, 0, 1); STG(Bb, 1, 3, 1, 1);
  asm volatile("s_waitcnt vmcnt(4)" ::: "memory");
  __builtin_amdgcn_s_barrier();
  __builtin_amdgcn_sched_barrier(0);

  f32x4 acc[8][4];
  if constexpr (ADD) {
#pragma unroll
    for (int mh = 0; mh < 2; mh++)
#pragma unroll
      for (int m = 0; m < 4; m++)
#pragma unroll
        for (int nf = 0; nf < 4; nf++) {
          int r0 = bm * 256 + (w64 >> 2) * 128 + mh * 64 + m * 16 + q4 * 4;
          int col = bn * 256 + (w64 & 3) * 64 + nf * 16 + lm;
#pragma unroll
          for (int j = 0; j < 4; j++)
            acc[mh * 4 + m][nf][j] = bf2f(base_bf[(size_t)(r0 + j) * N + col]);
        }
  } else {
#pragma unroll
    for (int mf = 0; mf < 8; mf++)
#pragma unroll
      for (int nf = 0; nf < 4; nf++) acc[mf][nf] = (f32x4){0.f, 0.f, 0.f, 0.f};
  }

  bf16x8 a[4][2], b0[2][2], b1[2][2];
  for (int i = 0; i < nI; i++) {
    int t1 = 2 * i + 1, t2 = 2 * i + 2, t3 = 2 * i + 3;
    DSRA(0, 0); DSRB(0, b0, 0); STG(Ab, 1, 0, 0, t1);   // P1
    BARW; MMA(0, b0, 0); BARE;
    DSRB(0, b1, 2); STG(Ab, 1, 1, 1, t1);               // P2
    BARW; MMA(0, b1, 2); BARE;
    DSRA(0, 1); STG(Bb, 0, 2, 0, t2);                   // P3
    BARW; MMA(1, b1, 2); BARE;
    STG(Bb, 0, 3, 1, t2);                               // P4
    BARW; MMA(1, b0, 0);
    if (i < nI - 1) { asm volatile("s_waitcnt vmcnt(4)" ::: "memory"); }
    else            { asm volatile("s_waitcnt vmcnt(0)" ::: "memory"); }
    BARE;
    DSRA(1, 0); DSRB(1, b0, 0); STG(Ab, 0, 0, 0, t2);   // P5
    BARW; MMA(0, b0, 0); BARE;
    DSRB(1, b1, 2); STG(Ab, 0, 1, 1, t2);               // P6
    BARW; MMA(0, b1, 2); BARE;
    DSRA(1, 1); STG(Bb, 1, 2, 0, t3);                   // P7
    BARW; MMA(1, b1, 2); BARE;
    STG(Bb, 1, 3, 1, t3);                               // P8
    BARW; MMA(1, b0, 0);
    if (i < nI - 1) { asm volatile("s_waitcnt vmcnt(4)" ::: "memory"); }
    BARE;
  }

#pragma unroll
  for (int mh = 0; mh < 2; mh++)
#pragma unroll
    for (int m = 0; m < 4; m++)
#pragma unroll
      for (int nf = 0; nf < 4; nf++) {
        int r0 = bm * 256 + (w64 >> 2) * 128 + mh * 64 + m * 16 + q4 * 4;
        int col = bn * 256 + (w64 & 3) * 64 + nf * 16 + lm;
#pragma unroll
        for (int j = 0; j < 4; j++) {
          if constexpr (ADD)
            ((float*)Cout)[(size_t)(r0 + j) * N + col] = acc[mh * 4 + m][nf][j];
          else
            ((unsigned short*)Cout)[(size_t)(r0 + j) * N + col] = f2bf(acc[mh * 4 + m][nf][j]);
        }
      }
}

// ---------------------------------------------------------------- per-chunk local work
__global__ __launch_bounds__(256) void chunk_local(
    const unsigned short* __restrict__ rkg,   // outbf flat [B*T*D]
    const unsigned short* __restrict__ vg,    // vbf flat
    const float* __restrict__ decay,
    unsigned short* __restrict__ intra_bf,    // flat [B*T*D]
    unsigned short* __restrict__ U_bf) {      // [BH][64][64*64]
  int c = blockIdx.x, bh = blockIdx.y;
  int b = bh >> 4, h = bh & 15;
  int tid = threadIdx.x, l = tid & 63, w = tid >> 6;
  float gamma = 1.0f / (1.0f + __expf(-decay[h]));
  float lg = __logf(gamma);

  __shared__ unsigned short kr_s[65 * 72];   // kr_s[p] = token c*64-1+p (p=0..64)
  __shared__ unsigned short wkT_s[64 * 72];  // transpose of kr_s rows 0..63
  __shared__ unsigned short vT_s[64 * 72];
  __shared__ unsigned short S_s[64 * 72];
  __shared__ float pw_s[64];                 // gamma^d

  if (tid < 64) pw_s[tid] = __expf(lg * (float)tid);

  const size_t rowbase = (((size_t)b * 4096 + (size_t)c * 64) * 1024) + h * 64;
  const size_t bb = (size_t)b * 4096;

#pragma unroll
  for (int r = 0; r < 2; r++) {
    int e = r * 256 + tid;
    int p = e >> 3, seg = e & 7;
    uint4 dv = *(const uint4*)(vg + rowbase + (size_t)p * 1024 + seg * 8);
    {
      unsigned uu[4] = {dv.x, dv.y, dv.z, dv.w};
#pragma unroll
      for (int qq = 0; qq < 4; qq++) {
        vT_s[(seg * 8 + qq * 2) * 72 + p] = (unsigned short)(uu[qq] & 0xffffu);
        vT_s[(seg * 8 + qq * 2 + 1) * 72 + p] = (unsigned short)(uu[qq] >> 16);
      }
    }
    int tg = c * 64 - 1 + p;
    uint4 dw = make_uint4(0u, 0u, 0u, 0u);
    if (tg >= 0) dw = *(const uint4*)(rkg + (bb + tg) * 1024 + h * 64 + seg * 8);
    *(uint4*)&kr_s[p * 72 + seg * 8] = dw;
    {
      unsigned uu[4] = {dw.x, dw.y, dw.z, dw.w};
#pragma unroll
      for (int qq = 0; qq < 4; qq++) {
        wkT_s[(seg * 8 + qq * 2) * 72 + p] = (unsigned short)(uu[qq] & 0xffffu);
        wkT_s[(seg * 8 + qq * 2 + 1) * 72 + p] = (unsigned short)(uu[qq] >> 16);
      }
    }
  }
  if (tid < 8) {
    uint4 dw = *(const uint4*)(rkg + (bb + (size_t)c * 64 + 63) * 1024 + h * 64 + tid * 8);
    *(uint4*)&kr_s[64 * 72 + tid * 8] = dw;
  }
  __syncthreads();

  int lm = l & 15, q4 = l >> 4;

  // Phase 1: S = rk @ wk^T, mask, bf16
  {
    bf16x8 a0 = *(const bf16x8*)&kr_s[(w * 16 + lm + 1) * 72 + q4 * 8];
    bf16x8 a1 = *(const bf16x8*)&kr_s[(w * 16 + lm + 1) * 72 + 32 + q4 * 8];
#pragma unroll
    for (int ni = 0; ni < 4; ni++) {
      bf16x8 b0 = *(const bf16x8*)&kr_s[(ni * 16 + lm) * 72 + q4 * 8];
      bf16x8 b1 = *(const bf16x8*)&kr_s[(ni * 16 + lm) * 72 + 32 + q4 * 8];
      f32x4 acc = {0.f, 0.f, 0.f, 0.f};
      acc = __builtin_amdgcn_mfma_f32_16x16x32_bf16(a0, b0, acc, 0, 0, 0);
      acc = __builtin_amdgcn_mfma_f32_16x16x32_bf16(a1, b1, acc, 0, 0, 0);
#pragma unroll
      for (int j = 0; j < 4; j++) {
        int p = w * 16 + q4 * 4 + j;
        int q = ni * 16 + lm;
        float m = (p > q) ? pw_s[p - 1 - q] : 0.0f;
        S_s[p * 72 + q] = f2bf(acc[j] * m);
      }
    }
  }
  __syncthreads();

  // Phase 2: intra = (S.M) @ v
  {
    bf16x8 a0 = *(const bf16x8*)&S_s[(w * 16 + lm) * 72 + q4 * 8];
    bf16x8 a1 = *(const bf16x8*)&S_s[(w * 16 + lm) * 72 + 32 + q4 * 8];
#pragma unroll
    for (int ni = 0; ni < 4; ni++) {
      bf16x8 b0 = *(const bf16x8*)&vT_s[(ni * 16 + lm) * 72 + q4 * 8];
      bf16x8 b1 = *(const bf16x8*)&vT_s[(ni * 16 + lm) * 72 + 32 + q4 * 8];
      f32x4 acc = {0.f, 0.f, 0.f, 0.f};
      acc = __builtin_amdgcn_mfma_f32_16x16x32_bf16(a0, b0, acc, 0, 0, 0);
      acc = __builtin_amdgcn_mfma_f32_16x16x32_bf16(a1, b1, acc, 0, 0, 0);
#pragma unroll
      for (int j = 0; j < 4; j++) {
        int p = w * 16 + q4 * 4 + j;
        int i = ni * 16 + lm;
        intra_bf[rowbase + (size_t)p * 1024 + i] = f2bf(acc[j]);
      }
    }
  }

  // Phase 3: U = (v * g_w)^T @ wk
  {
    bf16x8 a0 = *(const bf16x8*)&vT_s[(w * 16 + lm) * 72 + q4 * 8];
    bf16x8 a1 = *(const bf16x8*)&vT_s[(w * 16 + lm) * 72 + 32 + q4 * 8];
#pragma unroll
    for (int jj = 0; jj < 8; jj++) {
      int p0 = q4 * 8 + jj;
      a0[jj] = (__bf16)((float)a0[jj] * pw_s[63 - p0]);
      a1[jj] = (__bf16)((float)a1[jj] * pw_s[63 - (p0 + 32)]);
    }
    size_t ub = ((size_t)bh * 64 + c) * 4096;
#pragma unroll
    for (int nj = 0; nj < 4; nj++) {
      bf16x8 b0 = *(const bf16x8*)&wkT_s[(nj * 16 + lm) * 72 + q4 * 8];
      bf16x8 b1 = *(const bf16x8*)&wkT_s[(nj * 16 + lm) * 72 + 32 + q4 * 8];
      f32x4 acc = {0.f, 0.f, 0.f, 0.f};
      acc = __builtin_amdgcn_mfma_f32_16x16x32_bf16(a0, b0, acc, 0, 0, 0);
      acc = __builtin_amdgcn_mfma_f32_16x16x32_bf16(a1, b1, acc, 0, 0, 0);
#pragma unroll
      for (int j = 0; j < 4; j++) {
        int i = w * 16 + q4 * 4 + j;
        int col = nj * 16 + lm;
        U_bf[ub + i * 64 + col] = f2bf(acc[j]);
      }
    }
  }
}

// ---------------------------------------------------------------- parallel weighted prefix scan
__global__ __launch_bounds__(256) void scan_w(
    const unsigned short* __restrict__ U_bf, const float* __restrict__ decay,
    unsigned short* __restrict__ Wst) {
  int nsl = blockIdx.x, bh = blockIdx.y;
  int h = bh & 15;
  float gamma = 1.0f / (1.0f + __expf(-decay[h]));
  float gC = __expf(64.0f * __logf(gamma));
  int n0 = nsl * 1024 + threadIdx.x * 4;
  const unsigned short* Ub = U_bf + (size_t)bh * 64 * 4096 + n0;
  unsigned short* Wb = Wst + (size_t)bh * 64 * 4096 + n0;
  float w0 = 0.f, w1 = 0.f, w2 = 0.f, w3 = 0.f;
#pragma unroll
  for (int c = 0; c < 64; c++) {
    uint2 u = *(const uint2*)(Ub + (size_t)c * 4096);
    ushort4 sv;
    sv.x = f2bf(w0); sv.y = f2bf(w1); sv.z = f2bf(w2); sv.w = f2bf(w3);
    *(ushort4*)(Wb + (size_t)c * 4096) = sv;
    w0 = gC * w0 + bf2f((unsigned short)(u.x & 0xffffu));
    w1 = gC * w1 + bf2f((unsigned short)(u.x >> 16));
    w2 = gC * w2 + bf2f((unsigned short)(u.y & 0xffffu));
    w3 = gC * w3 + bf2f((unsigned short)(u.y >> 16));
  }
}

// ---------------------------------------------------------------- inter + combine (parallel)
__global__ __launch_bounds__(256) void inter_combine(
    const unsigned short* __restrict__ rkg, const unsigned short* __restrict__ Wst,
    const unsigned short* __restrict__ intra_bf,
    const float* __restrict__ decay, const float* __restrict__ log_alpha,
    unsigned short* __restrict__ reads_bf) {
  int c = blockIdx.x, bh = blockIdx.y;
  int b = bh >> 4, h = bh & 15;
  int tid = threadIdx.x, l = tid & 63, w = tid >> 6;
  int lm = l & 15, q4 = l >> 4;
  float gamma = 1.0f / (1.0f + __expf(-decay[h]));
  float lg = __logf(gamma);
  float alpha = __expf(log_alpha[h]);

  __shared__ unsigned short rk_s[64 * 72];
  __shared__ unsigned short W_s[64 * 72];
  __shared__ unsigned short in_s[64 * 72];

  const size_t rowbase = (((size_t)b * 4096 + (size_t)c * 64) * 1024) + h * 64;
  const size_t wbase = ((size_t)bh * 64 + c) * 4096;

#pragma unroll
  for (int r = 0; r < 2; r++) {
    int e = r * 256 + tid;
    int p = e >> 3, seg = (e & 7) * 8;
    *(uint4*)&rk_s[p * 72 + seg] = *(const uint4*)(rkg + rowbase + (size_t)p * 1024 + seg);
    *(uint4*)&in_s[p * 72 + seg] = *(const uint4*)(intra_bf + rowbase + (size_t)p * 1024 + seg);
    *(uint4*)&W_s[p * 72 + seg] = *(const uint4*)(Wst + wbase + (size_t)p * 64 + seg);
  }
  __syncthreads();

  bf16x8 a0 = *(const bf16x8*)&rk_s[(w * 16 + lm) * 72 + q4 * 8];
  bf16x8 a1 = *(const bf16x8*)&rk_s[(w * 16 + lm) * 72 + 32 + q4 * 8];
#pragma unroll
  for (int ni = 0; ni < 4; ni++) {
    bf16x8 b0 = *(const bf16x8*)&W_s[(ni * 16 + lm) * 72 + q4 * 8];
    bf16x8 b1 = *(const bf16x8*)&W_s[(ni * 16 + lm) * 72 + 32 + q4 * 8];
    f32x4 acc = {0.f, 0.f, 0.f, 0.f};
    acc = __builtin_amdgcn_mfma_f32_16x16x32_bf16(a0, b0, acc, 0, 0, 0);
    acc = __builtin_amdgcn_mfma_f32_16x16x32_bf16(a1, b1, acc, 0, 0, 0);
#pragma unroll
    for (int j = 0; j < 4; j++) {
      int p = w * 16 + q4 * 4 + j;
      int i = ni * 16 + lm;
      float gp = __expf(lg * (float)p);
      reads_bf[rowbase + (size_t)p * 1024 + i] =
          f2bf(alpha * (acc[j] * gp + bf2f(in_s[p * 72 + i])));
    }
  }
}

// ----------------------------------------------------------------
extern "C" void kernel_launch(void* const* d_in, const int* in_sizes, int n_in,
                              void* d_out, int out_size, void* d_ws, size_t ws_size,
                              hipStream_t stream) {
  const float* out_f = (const float*)d_in[0];
  const float* Ww = (const float*)d_in[1];
  const float* Wr = (const float*)d_in[2];
  const float* decay = (const float*)d_in[3];
  const float* lalpha = (const float*)d_in[4];

  char* ws = (char*)d_ws;
  unsigned short* outbf = (unsigned short*)(ws + 0);
  unsigned short* vbf   = (unsigned short*)(ws + 33554432);
  unsigned short* wwbf  = (unsigned short*)(ws + 67108864);  // wrbf adjacent at +2MB
  unsigned short* wrbf  = (unsigned short*)(ws + 69206016);
  unsigned short* intra = (unsigned short*)(ws + 71303168);
  unsigned short* U     = (unsigned short*)(ws + 104857600);
  unsigned short* Wst   = (unsigned short*)(ws + 138412032);
  unsigned short* reads = (unsigned short*)(ws + 171966464);

  cast_all<<<dim3(9216), 256, 0, stream>>>(out_f, Ww, Wr, outbf, wwbf);

  // V = out @ W_write^T   (M=B*T=16384, N=D=1024, K=D=1024)
  gemm256<false><<<dim3(256), 512, 0, stream>>>(outbf, wwbf, nullptr, vbf, 16384, 1024, 1024);

  chunk_local<<<dim3(64, 64), 256, 0, stream>>>(outbf, vbf, decay, intra, U);

  scan_w<<<dim3(4, 64), 256, 0, stream>>>(U, decay, Wst);
  inter_combine<<<dim3(64, 64), 256, 0, stream>>>(outbf, Wst, intra, decay, lalpha, reads);

  // final = out + reads @ W_read^T (base added from bf16 copy)
  gemm256<true><<<dim3(256), 512, 0, stream>>>(reads, wrbf, outbf, d_out, 16384, 1024, 1024);
}